// Round 4
// baseline (756.430 us; speedup 1.0000x reference)
//
#include <hip/hip_runtime.h>
#include <hip/hip_bf16.h>
#include <math.h>

typedef __bf16 bf16_t;
typedef __attribute__((ext_vector_type(8))) __bf16 bf16x8;
typedef __attribute__((ext_vector_type(4))) __bf16 bf16x4;
typedef __attribute__((ext_vector_type(4))) float f32x4;

#define T_TOK 100352      // 32 * 3136 tokens (= Bw*N = 2048*49)
#define DIMC 256
#define HEADS 8
#define HD 32
#define NTOK 49
#define SHIFT3 3
#define HH 56
#define SCALE_QK 0.17677669529663687f

__device__ __forceinline__ int xrow_of(int rr) {
    int wi = rr / 49; int t = rr - wi * 49;
    int b = wi >> 6; int w64 = wi & 63;
    int wh = w64 >> 3, ww = w64 & 7;
    int i = t / 7, j = t - i * 7;
    int hy = wh * 7 + i, wy = ww * 7 + j;
    int hx = hy + SHIFT3; if (hx >= HH) hx -= HH;
    int wx = wy + SHIFT3; if (wx >= HH) wx -= HH;
    return b * (HH * HH) + hx * HH + wx;
}

// ---------------- weight transpose + bf16 cast:  W[K][Nc] -> WT[Nc][K] ----------------
__global__ __launch_bounds__(256) void transpose_cast(const float* __restrict__ W,
                                                      bf16_t* __restrict__ WT,
                                                      int K, int Nc) {
    int t = blockIdx.x * 256 + threadIdx.x;
    int k = t / Nc, c = t - k * Nc;
    WT[(size_t)c * K + k] = (bf16_t)W[t];
}

// ---------------- LayerNorm (+optional window gather) + bf16 cast ----------------
template <int MAP>
__global__ __launch_bounds__(256) void ln_kernel(const float* __restrict__ x,
                                                 const float* __restrict__ g,
                                                 const float* __restrict__ bsh,
                                                 bf16_t* __restrict__ out) {
    int wv = threadIdx.x >> 6, l = threadIdx.x & 63;
    int r = blockIdx.x * 4 + wv;
    int xr = MAP ? xrow_of(r) : r;
    float4 v = ((const float4*)(x + (size_t)xr * DIMC))[l];
    float s = v.x + v.y + v.z + v.w;
    float sq = v.x * v.x + v.y * v.y + v.z * v.z + v.w * v.w;
    #pragma unroll
    for (int off = 32; off; off >>= 1) {
        s += __shfl_down(s, off);
        sq += __shfl_down(sq, off);
    }
    s = __shfl(s, 0); sq = __shfl(sq, 0);
    float mean = s * (1.f / 256.f);
    float var = sq * (1.f / 256.f) - mean * mean;
    float rstd = rsqrtf(var + 1e-5f);
    float4 gv = ((const float4*)g)[l];
    float4 bv = ((const float4*)bsh)[l];
    bf16x4 o;
    o[0] = (bf16_t)((v.x - mean) * rstd * gv.x + bv.x);
    o[1] = (bf16_t)((v.y - mean) * rstd * gv.y + bv.y);
    o[2] = (bf16_t)((v.z - mean) * rstd * gv.z + bv.z);
    o[3] = (bf16_t)((v.w - mean) * rstd * gv.w + bv.w);
    *(bf16x4*)(out + (size_t)r * DIMC + l * 4) = o;
}

// ---------------- m97-style bf16 MFMA GEMM (128x128 tile, BK=32) + XCD swizzle ----------
template <int EPI>
__global__ __launch_bounds__(256) void gemm128(const bf16_t* __restrict__ A,
                                               const bf16_t* __restrict__ BT,
                                               const float* __restrict__ bias,
                                               int Nc, int K,
                                               bf16_t* __restrict__ outb,
                                               float* __restrict__ outf,
                                               const float* __restrict__ resid) {
    __shared__ bf16_t As[128 * 32];
    __shared__ bf16_t Bs[128 * 32];
    int tid = threadIdx.x;
    int wv = tid >> 6, l = tid & 63;
    int wr = wv >> 1, wc = wv & 1;
    int nTilesN = Nc >> 7;
    // XCD-chunked swizzle (grid always % 8 == 0): same-bm tiles share an XCD L2
    int qn = gridDim.x >> 3;
    int lb = (blockIdx.x & 7) * qn + (blockIdx.x >> 3);
    int bm = lb / nTilesN, bn = lb - bm * nTilesN;
    size_t row0 = (size_t)bm * 128;
    int col0 = bn * 128;

    const char* Abase = (const char*)(A + row0 * K);
    const char* Bbase = (const char*)(BT + (size_t)col0 * K);
    const size_t ldb = (size_t)K * 2;

    f32x4 acc[4][4] = {};
    const int lr = l & 15, lk = (l >> 4) * 8;
    const int aoff = (wr * 64 + lr) * 32 + lk;
    const int boff = (wc * 64 + lr) * 32 + lk;

    for (int kk = 0; kk < K; kk += 32) {
        #pragma unroll
        for (int it = 0; it < 2; ++it) {
            int t = tid + it * 256;
            int row = t >> 2, cb = (t & 3) * 16;
            __builtin_amdgcn_global_load_lds(
                (const __attribute__((address_space(1))) void*)(Abase + (size_t)row * ldb + (size_t)kk * 2 + cb),
                (__attribute__((address_space(3))) void*)((char*)As + t * 16), 16, 0, 0);
            __builtin_amdgcn_global_load_lds(
                (const __attribute__((address_space(1))) void*)(Bbase + (size_t)row * ldb + (size_t)kk * 2 + cb),
                (__attribute__((address_space(3))) void*)((char*)Bs + t * 16), 16, 0, 0);
        }
        __syncthreads();
        bf16x8 a[4], b[4];
        #pragma unroll
        for (int m = 0; m < 4; ++m) a[m] = *(const bf16x8*)(As + aoff + m * 16 * 32);
        #pragma unroll
        for (int n = 0; n < 4; ++n) b[n] = *(const bf16x8*)(Bs + boff + n * 16 * 32);
        #pragma unroll
        for (int m = 0; m < 4; ++m)
            #pragma unroll
            for (int n = 0; n < 4; ++n)
                acc[m][n] = __builtin_amdgcn_mfma_f32_16x16x32_bf16(a[m], b[n], acc[m][n], 0, 0, 0);
        __syncthreads();
    }

    #pragma unroll
    for (int m = 0; m < 4; ++m) {
        #pragma unroll
        for (int i = 0; i < 4; ++i) {
            int rr = (int)row0 + wr * 64 + m * 16 + (l >> 4) * 4 + i;
            size_t orow = (EPI == 3) ? (size_t)xrow_of(rr) * DIMC : (size_t)rr * Nc;
            #pragma unroll
            for (int n = 0; n < 4; ++n) {
                int cc = col0 + wc * 64 + n * 16 + (l & 15);
                float v = acc[m][n][i] + bias[cc];
                if (EPI == 0) {
                    outb[(size_t)rr * Nc + cc] = (bf16_t)v;
                } else if (EPI == 2) {
                    size_t o = (size_t)rr * Nc + cc;
                    outf[o] = v + resid[o];
                } else {
                    size_t o = orow + cc;
                    outf[o] = v + resid[o];
                }
            }
        }
    }
}

// ---------------- fused LN2 + MLP1 + GELU + MLP2 + residual ----------------
// One block (4 waves) per 64 rows. LN2 into reg A-frags; 8 phases of 128 hidden cols:
//   stage W1-slice [128][256] (64KB swz) -> 64 MFMA -> gelu -> wave-private hq (swz)
//   stage W2-slice [256][128] (64KB swz) -> 64 MFMA into acc.
// Epilogue: out = acc + b2 + resid (in-place on xio; rows block-private).
__global__ __launch_bounds__(256) void mlp_fused(const float* __restrict__ xio,
                                                 const float* __restrict__ g2,
                                                 const float* __restrict__ bsh2,
                                                 const bf16_t* __restrict__ w1t,   // [1024][256]
                                                 const float* __restrict__ bias1,  // [1024]
                                                 const bf16_t* __restrict__ w2t,   // [256][1024]
                                                 const float* __restrict__ bias2,  // [256]
                                                 float* __restrict__ outx) {
    __shared__ __align__(16) char Wsl[65536];
    __shared__ __align__(16) char hq[16384];
    int tid = threadIdx.x, wv = tid >> 6, l = tid & 63;
    int g4 = l >> 4, lr = l & 15;
    int qn = gridDim.x >> 3;
    int lb = (blockIdx.x & 7) * qn + (blockIdx.x >> 3);
    size_t rows0 = (size_t)lb * 64;
    int myrow = (int)rows0 + wv * 16 + lr;

    // ---- LN2 of own row into A-frags: frag f covers k = f*32 + g4*8 .. +8 ----
    const float* xr = xio + (size_t)myrow * 256;
    float xv[8][8];
    float s = 0.f, sq = 0.f;
    #pragma unroll
    for (int f = 0; f < 8; ++f) {
        float4 u0 = *(const float4*)(xr + f * 32 + g4 * 8);
        float4 u1 = *(const float4*)(xr + f * 32 + g4 * 8 + 4);
        xv[f][0] = u0.x; xv[f][1] = u0.y; xv[f][2] = u0.z; xv[f][3] = u0.w;
        xv[f][4] = u1.x; xv[f][5] = u1.y; xv[f][6] = u1.z; xv[f][7] = u1.w;
        s  += u0.x + u0.y + u0.z + u0.w + u1.x + u1.y + u1.z + u1.w;
        sq += u0.x*u0.x + u0.y*u0.y + u0.z*u0.z + u0.w*u0.w
            + u1.x*u1.x + u1.y*u1.y + u1.z*u1.z + u1.w*u1.w;
    }
    s  += __shfl_xor(s, 16);  s  += __shfl_xor(s, 32);
    sq += __shfl_xor(sq, 16); sq += __shfl_xor(sq, 32);
    float mean = s * (1.f / 256.f);
    float rstd = rsqrtf(sq * (1.f / 256.f) - mean * mean + 1e-5f);
    bf16x8 a[8];
    #pragma unroll
    for (int f = 0; f < 8; ++f) {
        float4 gv0 = *(const float4*)(g2 + f * 32 + g4 * 8);
        float4 gv1 = *(const float4*)(g2 + f * 32 + g4 * 8 + 4);
        float4 bv0 = *(const float4*)(bsh2 + f * 32 + g4 * 8);
        float4 bv1 = *(const float4*)(bsh2 + f * 32 + g4 * 8 + 4);
        float gg[8] = {gv0.x, gv0.y, gv0.z, gv0.w, gv1.x, gv1.y, gv1.z, gv1.w};
        float bb[8] = {bv0.x, bv0.y, bv0.z, bv0.w, bv1.x, bv1.y, bv1.z, bv1.w};
        #pragma unroll
        for (int j = 0; j < 8; ++j)
            a[f][j] = (bf16_t)((xv[f][j] - mean) * rstd * gg[j] + bb[j]);
    }

    f32x4 acc[16] = {};
    char* HB = hq + wv * 4096;

    for (int p = 0; p < 8; ++p) {
        // ---- stage W1 slice [128 c][256 k], swizzled byte ^= ((c&7)<<4) ----
        __syncthreads();
        #pragma unroll
        for (int it = 0; it < 16; ++it) {
            int t = tid + it * 256;                 // 4096 x 16B
            int c = t >> 5, kc = (t & 31) ^ (c & 7);
            __builtin_amdgcn_global_load_lds(
                (const __attribute__((address_space(1))) void*)((const char*)w1t + ((size_t)(p * 128 + c) * 256 + kc * 8) * 2),
                (__attribute__((address_space(3))) void*)(Wsl + t * 16), 16, 0, 0);
        }
        __syncthreads();
        // ---- mlp1-sub: c1[64][128], this wave's 16 rows ----
        f32x4 c1[8] = {};
        #pragma unroll
        for (int ks = 0; ks < 8; ++ks) {
            #pragma unroll
            for (int n = 0; n < 8; ++n) {
                int c = n * 16 + lr;
                int byte = (c * 512 + ks * 64 + g4 * 16) ^ ((c & 7) << 4);
                bf16x8 b = *(const bf16x8*)(Wsl + byte);
                c1[n] = __builtin_amdgcn_mfma_f32_16x16x32_bf16(a[ks], b, c1[n], 0, 0, 0);
            }
        }
        // ---- gelu -> wave-private hq [16 r][128 c] bf16, swizzled ----
        #pragma unroll
        for (int n = 0; n < 8; ++n) {
            float b1v = bias1[p * 128 + n * 16 + lr];
            #pragma unroll
            for (int i = 0; i < 4; ++i) {
                int r4 = g4 * 4 + i;
                float v = c1[n][i] + b1v;
                float t3 = v + 0.044715f * v * v * v;
                float e = __expf(-1.5957691216057308f * t3);
                float gl = v * __builtin_amdgcn_rcpf(1.f + e);
                int byte = (r4 * 256 + (n * 16 + lr) * 2) ^ ((r4 & 7) << 4);
                *(bf16_t*)(HB + byte) = (bf16_t)gl;
            }
        }
        // ---- stage W2 slice [256 c][128 k], swizzled ----
        __syncthreads();
        #pragma unroll
        for (int it = 0; it < 16; ++it) {
            int t = tid + it * 256;
            int c = t >> 4, kc = (t & 15) ^ (c & 7);
            __builtin_amdgcn_global_load_lds(
                (const __attribute__((address_space(1))) void*)((const char*)w2t + ((size_t)c * 1024 + p * 128 + kc * 8) * 2),
                (__attribute__((address_space(3))) void*)(Wsl + t * 16), 16, 0, 0);
        }
        __syncthreads();
        // ---- mlp2-sub: acc += hq @ W2slice ----
        #pragma unroll
        for (int ks = 0; ks < 4; ++ks) {
            int abyte = (lr * 256 + ks * 64 + g4 * 16) ^ ((lr & 7) << 4);
            bf16x8 a2 = *(const bf16x8*)(HB + abyte);
            #pragma unroll
            for (int n = 0; n < 16; ++n) {
                int c = n * 16 + lr;
                int byte = (c * 256 + ks * 64 + g4 * 16) ^ ((c & 7) << 4);
                bf16x8 b = *(const bf16x8*)(Wsl + byte);
                acc[n] = __builtin_amdgcn_mfma_f32_16x16x32_bf16(a2, b, acc[n], 0, 0, 0);
            }
        }
    }

    // ---- epilogue: out = acc + bias2 + resid (in-place, rows block-private) ----
    #pragma unroll
    for (int n = 0; n < 16; ++n) {
        int cc = n * 16 + lr;
        float b2v = bias2[cc];
        #pragma unroll
        for (int i = 0; i < 4; ++i) {
            size_t o = (rows0 + wv * 16 + g4 * 4 + i) * 256 + cc;
            outx[o] = acc[n][i] + b2v + xio[o];
        }
    }
}

// ---------------- MFMA windowed attention ----------------
__global__ __launch_bounds__(256) void attn_mfma(const bf16_t* __restrict__ qkv,
                                                 const float* __restrict__ bt,
                                                 bf16_t* __restrict__ out) {
    __shared__ __align__(16) char lds[4][12800];
    int wv = threadIdx.x >> 6, l = threadIdx.x & 63;
    int head = ((blockIdx.x & 1) << 2) | wv;
    int wi = blockIdx.x >> 1;
    char* W = lds[wv];
    bf16_t* Vt = (bf16_t*)(W + 8192);          // [32][72]
    size_t rowbase = (size_t)wi * NTOK;
    const bf16_t* src = qkv + rowbase * 768 + head * HD;

    int w64 = wi & 63;
    int wh = w64 >> 3, ww = w64 & 7;
    bool lastH = (wh == 7), lastW = (ww == 7);
    bool masked = lastH || lastW;

    #pragma unroll
    for (int it = 0; it < 4; ++it) {
        int t = l + it * 64;
        int r = t >> 2, g = t & 3;
        if (r < NTOK) {
            bf16x8 qv = *(const bf16x8*)(src + (size_t)r * 768 + g * 8);
            bf16x8 kv = *(const bf16x8*)(src + (size_t)r * 768 + 256 + g * 8);
            int sa = (r * 64 + g * 16) ^ ((r & 7) << 4);
            *(bf16x8*)(W + sa) = qv;
            *(bf16x8*)(W + 4096 + sa) = kv;
        }
    }
    #pragma unroll
    for (int it = 0; it < 4; ++it) {
        int t = l + it * 64;
        int m = t >> 2, dc = t & 3;
        if (m < NTOK) {
            bf16x8 vv = *(const bf16x8*)(src + (size_t)m * 768 + 512 + dc * 8);
            #pragma unroll
            for (int j = 0; j < 8; ++j) Vt[(dc * 8 + j) * 72 + m] = vv[j];
        } else {
            #pragma unroll
            for (int j = 0; j < 8; ++j) Vt[(dc * 8 + j) * 72 + m] = (bf16_t)0.f;
        }
    }

    int lr = l & 15, g4 = l >> 4;

    bf16x8 a[4], b[4];
    #pragma unroll
    for (int mt = 0; mt < 4; ++mt) {
        int r = mt * 16 + lr;
        int sa = (r * 64 + g4 * 16) ^ ((r & 7) << 4);
        a[mt] = *(const bf16x8*)(W + sa);
        b[mt] = *(const bf16x8*)(W + 4096 + sa);
    }
    f32x4 z = {0.f, 0.f, 0.f, 0.f};
    f32x4 S[4][4];
    #pragma unroll
    for (int mt = 0; mt < 4; ++mt)
        #pragma unroll
        for (int nt = 0; nt < 4; ++nt)
            S[mt][nt] = __builtin_amdgcn_mfma_f32_16x16x32_bf16(a[mt], b[nt], z, 0, 0, 0);

    int i2[4], j2[4], reg2[4];
    #pragma unroll
    for (int nt = 0; nt < 4; ++nt) {
        int cm = nt * 16 + lr;
        i2[nt] = (cm * 147) >> 10;
        j2[nt] = cm - i2[nt] * 7;
        int rh = lastH ? ((i2[nt] < 4) ? 1 : 2) : 0;
        int rw = lastW ? ((j2[nt] < 4) ? 1 : 2) : 0;
        reg2[nt] = rh * 3 + rw;
    }

    #pragma unroll
    for (int mt = 0; mt < 4; ++mt) {
        #pragma unroll
        for (int i = 0; i < 4; ++i) {
            int rn = mt * 16 + g4 * 4 + i;
            bool rowok = rn < NTOK;
            int i1 = (rn * 147) >> 10, j1 = rn - i1 * 7;
            int rh1 = lastH ? ((i1 < 4) ? 1 : 2) : 0;
            int rw1 = lastW ? ((j1 < 4) ? 1 : 2) : 0;
            int reg1 = rh1 * 3 + rw1;
            float sv[4];
            #pragma unroll
            for (int nt = 0; nt < 4; ++nt) {
                int cm = nt * 16 + lr;
                float sc;
                if (rowok && cm < NTOK) {
                    sc = S[mt][nt][i] * SCALE_QK;
                    sc += bt[((i1 - i2[nt] + 6) + 13 * (j1 - j2[nt] + 6)) * 8 + head];
                    if (masked && (reg1 != reg2[nt])) sc -= 100.f;
                } else {
                    sc = -1e30f;
                }
                sv[nt] = sc;
            }
            float mx = fmaxf(fmaxf(sv[0], sv[1]), fmaxf(sv[2], sv[3]));
            mx = fmaxf(mx, __shfl_xor(mx, 1));
            mx = fmaxf(mx, __shfl_xor(mx, 2));
            mx = fmaxf(mx, __shfl_xor(mx, 4));
            mx = fmaxf(mx, __shfl_xor(mx, 8));
            float e[4];
            float sum = 0.f;
            #pragma unroll
            for (int nt = 0; nt < 4; ++nt) { e[nt] = __expf(sv[nt] - mx); sum += e[nt]; }
            sum += __shfl_xor(sum, 1);
            sum += __shfl_xor(sum, 2);
            sum += __shfl_xor(sum, 4);
            sum += __shfl_xor(sum, 8);
            float inv = 1.f / sum;
            #pragma unroll
            for (int nt = 0; nt < 4; ++nt) {
                int cm = nt * 16 + lr;
                int pa = (rn * 128 + cm * 2) ^ ((rn & 7) << 4);
                *(bf16_t*)(W + pa) = (bf16_t)(e[nt] * inv);
            }
        }
    }

    f32x4 o[4][2] = {};
    #pragma unroll
    for (int ks = 0; ks < 2; ++ks) {
        bf16x8 pa[4], vb[2];
        #pragma unroll
        for (int mt = 0; mt < 4; ++mt) {
            int r = mt * 16 + lr;
            int ad = (r * 128 + ks * 64 + g4 * 16) ^ ((r & 7) << 4);
            pa[mt] = *(const bf16x8*)(W + ad);
        }
        #pragma unroll
        for (int dt = 0; dt < 2; ++dt) {
            int d = dt * 16 + lr;
            vb[dt] = *(const bf16x8*)((char*)Vt + d * 144 + ks * 64 + g4 * 16);
        }
        #pragma unroll
        for (int mt = 0; mt < 4; ++mt)
            #pragma unroll
            for (int dt = 0; dt < 2; ++dt)
                o[mt][dt] = __builtin_amdgcn_mfma_f32_16x16x32_bf16(pa[mt], vb[dt], o[mt][dt], 0, 0, 0);
    }

    #pragma unroll
    for (int mt = 0; mt < 4; ++mt) {
        #pragma unroll
        for (int i = 0; i < 4; ++i) {
            int n = mt * 16 + g4 * 4 + i;
            if (n < NTOK) {
                #pragma unroll
                for (int dt = 0; dt < 2; ++dt) {
                    out[(rowbase + n) * DIMC + head * HD + dt * 16 + lr] = (bf16_t)o[mt][dt][i];
                }
            }
        }
    }
}

extern "C" void kernel_launch(void* const* d_in, const int* in_sizes, int n_in,
                              void* d_out, int out_size, void* d_ws, size_t ws_size,
                              hipStream_t stream) {
    const float* x      = (const float*)d_in[0];
    const float* n1g    = (const float*)d_in[1];
    const float* n1b    = (const float*)d_in[2];
    const float* qkv_w  = (const float*)d_in[3];
    const float* qkv_b  = (const float*)d_in[4];
    const float* proj_w = (const float*)d_in[5];
    const float* proj_b = (const float*)d_in[6];
    const float* btab   = (const float*)d_in[7];
    const float* n2g    = (const float*)d_in[8];
    const float* n2b    = (const float*)d_in[9];
    const float* w1     = (const float*)d_in[10];
    const float* b1     = (const float*)d_in[11];
    const float* w2     = (const float*)d_in[12];
    const float* b2     = (const float*)d_in[13];

    char* ws = (char*)d_ws;
    bf16_t* win      = (bf16_t*)(ws);
    bf16_t* qkvbuf   = (bf16_t*)(ws + (size_t)T_TOK * 256 * 2);
    char* wtp        = ws + (size_t)T_TOK * 2048 + (size_t)T_TOK * 512;
    bf16_t* wt_qkv   = (bf16_t*)wtp;               // [768][256]
    bf16_t* wt_proj  = wt_qkv + 768 * 256;         // [256][256]
    bf16_t* wt_mlp1  = wt_proj + 256 * 256;        // [1024][256]
    bf16_t* wt_mlp2  = wt_mlp1 + 1024 * 256;       // [256][1024]
    float* xmid      = (float*)d_out;

    transpose_cast<<<768, 256, 0, stream>>>(qkv_w, wt_qkv, 256, 768);
    transpose_cast<<<256, 256, 0, stream>>>(proj_w, wt_proj, 256, 256);
    transpose_cast<<<1024, 256, 0, stream>>>(w1, wt_mlp1, 256, 1024);
    transpose_cast<<<1024, 256, 0, stream>>>(w2, wt_mlp2, 1024, 256);

    ln_kernel<1><<<T_TOK / 4, 256, 0, stream>>>(x, n1g, n1b, win);
    // QKV GEMM  [T,256] x [256,768]
    gemm128<0><<<(T_TOK / 128) * (768 / 128), 256, 0, stream>>>(win, wt_qkv, qkv_b, 768, 256,
                                                                qkvbuf, nullptr, nullptr);
    attn_mfma<<<2048 * 2, 256, 0, stream>>>(qkvbuf, btab, win);
    // proj GEMM + window reverse + unshift + residual -> xmid (= d_out)
    gemm128<3><<<(T_TOK / 128) * (256 / 128), 256, 0, stream>>>(win, wt_proj, proj_b, 256, 256,
                                                                nullptr, xmid, x);
    // fused LN2 + MLP (in-place on xmid)
    mlp_fused<<<T_TOK / 64, 256, 0, stream>>>(xmid, n2g, n2b, wt_mlp1, b1, wt_mlp2, b2, xmid);
}

// Round 5
// 585.414 us; speedup vs baseline: 1.2921x; 1.2921x over previous
//
#include <hip/hip_runtime.h>
#include <hip/hip_bf16.h>
#include <math.h>

typedef __bf16 bf16_t;
typedef __attribute__((ext_vector_type(8))) __bf16 bf16x8;
typedef __attribute__((ext_vector_type(4))) __bf16 bf16x4;
typedef __attribute__((ext_vector_type(4))) float f32x4;

#define T_TOK 100352      // 32 * 3136 tokens (= Bw*N = 2048*49)
#define DIMC 256
#define HEADS 8
#define HD 32
#define NTOK 49
#define SHIFT3 3
#define HH 56
#define SCALE_QK 0.17677669529663687f

__device__ __forceinline__ int xrow_of(int rr) {
    int wi = rr / 49; int t = rr - wi * 49;
    int b = wi >> 6; int w64 = wi & 63;
    int wh = w64 >> 3, ww = w64 & 7;
    int i = t / 7, j = t - i * 7;
    int hy = wh * 7 + i, wy = ww * 7 + j;
    int hx = hy + SHIFT3; if (hx >= HH) hx -= HH;
    int wx = wy + SHIFT3; if (wx >= HH) wx -= HH;
    return b * (HH * HH) + hx * HH + wx;
}

// ---------------- weight transpose + bf16 cast:  W[K][Nc] -> WT[Nc][K] ----------------
__global__ __launch_bounds__(256) void transpose_cast(const float* __restrict__ W,
                                                      bf16_t* __restrict__ WT,
                                                      int K, int Nc) {
    int t = blockIdx.x * 256 + threadIdx.x;
    int k = t / Nc, c = t - k * Nc;
    WT[(size_t)c * K + k] = (bf16_t)W[t];
}

// ---------------- LayerNorm (+optional window gather) + bf16 cast ----------------
template <int MAP>
__global__ __launch_bounds__(256) void ln_kernel(const float* __restrict__ x,
                                                 const float* __restrict__ g,
                                                 const float* __restrict__ bsh,
                                                 bf16_t* __restrict__ out) {
    int wv = threadIdx.x >> 6, l = threadIdx.x & 63;
    int r = blockIdx.x * 4 + wv;
    int xr = MAP ? xrow_of(r) : r;
    float4 v = ((const float4*)(x + (size_t)xr * DIMC))[l];
    float s = v.x + v.y + v.z + v.w;
    float sq = v.x * v.x + v.y * v.y + v.z * v.z + v.w * v.w;
    #pragma unroll
    for (int off = 32; off; off >>= 1) {
        s += __shfl_down(s, off);
        sq += __shfl_down(sq, off);
    }
    s = __shfl(s, 0); sq = __shfl(sq, 0);
    float mean = s * (1.f / 256.f);
    float var = sq * (1.f / 256.f) - mean * mean;
    float rstd = rsqrtf(var + 1e-5f);
    float4 gv = ((const float4*)g)[l];
    float4 bv = ((const float4*)bsh)[l];
    bf16x4 o;
    o[0] = (bf16_t)((v.x - mean) * rstd * gv.x + bv.x);
    o[1] = (bf16_t)((v.y - mean) * rstd * gv.y + bv.y);
    o[2] = (bf16_t)((v.z - mean) * rstd * gv.z + bv.z);
    o[3] = (bf16_t)((v.w - mean) * rstd * gv.w + bv.w);
    *(bf16x4*)(out + (size_t)r * DIMC + l * 4) = o;
}

// ---------------- m97-style bf16 MFMA GEMM (128x128 tile, BK=32) + XCD swizzle ----------
// EPI: 0 = bias, bf16 | 1 = bias+gelu (exp-sigmoid), bf16 | 2 = bias+resid, f32 |
//      3 = bias + scatter to xrow_of(r) + resid, f32
template <int EPI>
__global__ __launch_bounds__(256) void gemm128(const bf16_t* __restrict__ A,
                                               const bf16_t* __restrict__ BT,
                                               const float* __restrict__ bias,
                                               int Nc, int K,
                                               bf16_t* __restrict__ outb,
                                               float* __restrict__ outf,
                                               const float* __restrict__ resid) {
    __shared__ bf16_t As[128 * 32];
    __shared__ bf16_t Bs[128 * 32];
    int tid = threadIdx.x;
    int wv = tid >> 6, l = tid & 63;
    int wr = wv >> 1, wc = wv & 1;
    int nTilesN = Nc >> 7;
    // XCD-chunked swizzle (grid always % 8 == 0): same-bm tiles share an XCD L2
    int qn = gridDim.x >> 3;
    int lb = (blockIdx.x & 7) * qn + (blockIdx.x >> 3);
    int bm = lb / nTilesN, bn = lb - bm * nTilesN;
    size_t row0 = (size_t)bm * 128;
    int col0 = bn * 128;

    const char* Abase = (const char*)(A + row0 * K);
    const char* Bbase = (const char*)(BT + (size_t)col0 * K);
    const size_t ldb = (size_t)K * 2;

    f32x4 acc[4][4] = {};
    const int lr = l & 15, lk = (l >> 4) * 8;
    const int aoff = (wr * 64 + lr) * 32 + lk;
    const int boff = (wc * 64 + lr) * 32 + lk;

    for (int kk = 0; kk < K; kk += 32) {
        #pragma unroll
        for (int it = 0; it < 2; ++it) {
            int t = tid + it * 256;
            int row = t >> 2, cb = (t & 3) * 16;
            __builtin_amdgcn_global_load_lds(
                (const __attribute__((address_space(1))) void*)(Abase + (size_t)row * ldb + (size_t)kk * 2 + cb),
                (__attribute__((address_space(3))) void*)((char*)As + t * 16), 16, 0, 0);
            __builtin_amdgcn_global_load_lds(
                (const __attribute__((address_space(1))) void*)(Bbase + (size_t)row * ldb + (size_t)kk * 2 + cb),
                (__attribute__((address_space(3))) void*)((char*)Bs + t * 16), 16, 0, 0);
        }
        __syncthreads();
        bf16x8 a[4], b[4];
        #pragma unroll
        for (int m = 0; m < 4; ++m) a[m] = *(const bf16x8*)(As + aoff + m * 16 * 32);
        #pragma unroll
        for (int n = 0; n < 4; ++n) b[n] = *(const bf16x8*)(Bs + boff + n * 16 * 32);
        #pragma unroll
        for (int m = 0; m < 4; ++m)
            #pragma unroll
            for (int n = 0; n < 4; ++n)
                acc[m][n] = __builtin_amdgcn_mfma_f32_16x16x32_bf16(a[m], b[n], acc[m][n], 0, 0, 0);
        __syncthreads();
    }

    #pragma unroll
    for (int m = 0; m < 4; ++m) {
        #pragma unroll
        for (int i = 0; i < 4; ++i) {
            int rr = (int)row0 + wr * 64 + m * 16 + (l >> 4) * 4 + i;
            size_t orow = (EPI == 3) ? (size_t)xrow_of(rr) * DIMC : (size_t)rr * Nc;
            #pragma unroll
            for (int n = 0; n < 4; ++n) {
                int cc = col0 + wc * 64 + n * 16 + (l & 15);
                float v = acc[m][n][i] + bias[cc];
                if (EPI == 0) {
                    outb[(size_t)rr * Nc + cc] = (bf16_t)v;
                } else if (EPI == 1) {
                    float t3 = v + 0.044715f * v * v * v;
                    float e = __expf(-1.5957691216057308f * t3);
                    float gl = v * __builtin_amdgcn_rcpf(1.f + e);
                    outb[(size_t)rr * Nc + cc] = (bf16_t)gl;
                } else if (EPI == 2) {
                    size_t o = (size_t)rr * Nc + cc;
                    outf[o] = v + resid[o];
                } else {
                    size_t o = orow + cc;
                    outf[o] = v + resid[o];
                }
            }
        }
    }
}

// ---------------- MFMA windowed attention ----------------
__global__ __launch_bounds__(256) void attn_mfma(const bf16_t* __restrict__ qkv,
                                                 const float* __restrict__ bt,
                                                 bf16_t* __restrict__ out) {
    __shared__ __align__(16) char lds[4][12800];
    int wv = threadIdx.x >> 6, l = threadIdx.x & 63;
    int head = ((blockIdx.x & 1) << 2) | wv;
    int wi = blockIdx.x >> 1;
    char* W = lds[wv];
    bf16_t* Vt = (bf16_t*)(W + 8192);          // [32][72]
    size_t rowbase = (size_t)wi * NTOK;
    const bf16_t* src = qkv + rowbase * 768 + head * HD;

    int w64 = wi & 63;
    int wh = w64 >> 3, ww = w64 & 7;
    bool lastH = (wh == 7), lastW = (ww == 7);
    bool masked = lastH || lastW;

    #pragma unroll
    for (int it = 0; it < 4; ++it) {
        int t = l + it * 64;
        int r = t >> 2, g = t & 3;
        if (r < NTOK) {
            bf16x8 qv = *(const bf16x8*)(src + (size_t)r * 768 + g * 8);
            bf16x8 kv = *(const bf16x8*)(src + (size_t)r * 768 + 256 + g * 8);
            int sa = (r * 64 + g * 16) ^ ((r & 7) << 4);
            *(bf16x8*)(W + sa) = qv;
            *(bf16x8*)(W + 4096 + sa) = kv;
        }
    }
    #pragma unroll
    for (int it = 0; it < 4; ++it) {
        int t = l + it * 64;
        int m = t >> 2, dc = t & 3;
        if (m < NTOK) {
            bf16x8 vv = *(const bf16x8*)(src + (size_t)m * 768 + 512 + dc * 8);
            #pragma unroll
            for (int j = 0; j < 8; ++j) Vt[(dc * 8 + j) * 72 + m] = vv[j];
        } else {
            #pragma unroll
            for (int j = 0; j < 8; ++j) Vt[(dc * 8 + j) * 72 + m] = (bf16_t)0.f;
        }
    }

    int lr = l & 15, g4 = l >> 4;

    bf16x8 a[4], b[4];
    #pragma unroll
    for (int mt = 0; mt < 4; ++mt) {
        int r = mt * 16 + lr;
        int sa = (r * 64 + g4 * 16) ^ ((r & 7) << 4);
        a[mt] = *(const bf16x8*)(W + sa);
        b[mt] = *(const bf16x8*)(W + 4096 + sa);
    }
    f32x4 z = {0.f, 0.f, 0.f, 0.f};
    f32x4 S[4][4];
    #pragma unroll
    for (int mt = 0; mt < 4; ++mt)
        #pragma unroll
        for (int nt = 0; nt < 4; ++nt)
            S[mt][nt] = __builtin_amdgcn_mfma_f32_16x16x32_bf16(a[mt], b[nt], z, 0, 0, 0);

    int i2[4], j2[4], reg2[4];
    #pragma unroll
    for (int nt = 0; nt < 4; ++nt) {
        int cm = nt * 16 + lr;
        i2[nt] = (cm * 147) >> 10;
        j2[nt] = cm - i2[nt] * 7;
        int rh = lastH ? ((i2[nt] < 4) ? 1 : 2) : 0;
        int rw = lastW ? ((j2[nt] < 4) ? 1 : 2) : 0;
        reg2[nt] = rh * 3 + rw;
    }

    #pragma unroll
    for (int mt = 0; mt < 4; ++mt) {
        #pragma unroll
        for (int i = 0; i < 4; ++i) {
            int rn = mt * 16 + g4 * 4 + i;
            bool rowok = rn < NTOK;
            int i1 = (rn * 147) >> 10, j1 = rn - i1 * 7;
            int rh1 = lastH ? ((i1 < 4) ? 1 : 2) : 0;
            int rw1 = lastW ? ((j1 < 4) ? 1 : 2) : 0;
            int reg1 = rh1 * 3 + rw1;
            float sv[4];
            #pragma unroll
            for (int nt = 0; nt < 4; ++nt) {
                int cm = nt * 16 + lr;
                float sc;
                if (rowok && cm < NTOK) {
                    sc = S[mt][nt][i] * SCALE_QK;
                    sc += bt[((i1 - i2[nt] + 6) + 13 * (j1 - j2[nt] + 6)) * 8 + head];
                    if (masked && (reg1 != reg2[nt])) sc -= 100.f;
                } else {
                    sc = -1e30f;
                }
                sv[nt] = sc;
            }
            float mx = fmaxf(fmaxf(sv[0], sv[1]), fmaxf(sv[2], sv[3]));
            mx = fmaxf(mx, __shfl_xor(mx, 1));
            mx = fmaxf(mx, __shfl_xor(mx, 2));
            mx = fmaxf(mx, __shfl_xor(mx, 4));
            mx = fmaxf(mx, __shfl_xor(mx, 8));
            float e[4];
            float sum = 0.f;
            #pragma unroll
            for (int nt = 0; nt < 4; ++nt) { e[nt] = __expf(sv[nt] - mx); sum += e[nt]; }
            sum += __shfl_xor(sum, 1);
            sum += __shfl_xor(sum, 2);
            sum += __shfl_xor(sum, 4);
            sum += __shfl_xor(sum, 8);
            float inv = 1.f / sum;
            #pragma unroll
            for (int nt = 0; nt < 4; ++nt) {
                int cm = nt * 16 + lr;
                int pa = (rn * 128 + cm * 2) ^ ((rn & 7) << 4);
                *(bf16_t*)(W + pa) = (bf16_t)(e[nt] * inv);
            }
        }
    }

    f32x4 o[4][2] = {};
    #pragma unroll
    for (int ks = 0; ks < 2; ++ks) {
        bf16x8 pa[4], vb[2];
        #pragma unroll
        for (int mt = 0; mt < 4; ++mt) {
            int r = mt * 16 + lr;
            int ad = (r * 128 + ks * 64 + g4 * 16) ^ ((r & 7) << 4);
            pa[mt] = *(const bf16x8*)(W + ad);
        }
        #pragma unroll
        for (int dt = 0; dt < 2; ++dt) {
            int d = dt * 16 + lr;
            vb[dt] = *(const bf16x8*)((char*)Vt + d * 144 + ks * 64 + g4 * 16);
        }
        #pragma unroll
        for (int mt = 0; mt < 4; ++mt)
            #pragma unroll
            for (int dt = 0; dt < 2; ++dt)
                o[mt][dt] = __builtin_amdgcn_mfma_f32_16x16x32_bf16(pa[mt], vb[dt], o[mt][dt], 0, 0, 0);
    }

    #pragma unroll
    for (int mt = 0; mt < 4; ++mt) {
        #pragma unroll
        for (int i = 0; i < 4; ++i) {
            int n = mt * 16 + g4 * 4 + i;
            if (n < NTOK) {
                #pragma unroll
                for (int dt = 0; dt < 2; ++dt) {
                    out[(rowbase + n) * DIMC + head * HD + dt * 16 + lr] = (bf16_t)o[mt][dt][i];
                }
            }
        }
    }
}

extern "C" void kernel_launch(void* const* d_in, const int* in_sizes, int n_in,
                              void* d_out, int out_size, void* d_ws, size_t ws_size,
                              hipStream_t stream) {
    const float* x      = (const float*)d_in[0];
    const float* n1g    = (const float*)d_in[1];
    const float* n1b    = (const float*)d_in[2];
    const float* qkv_w  = (const float*)d_in[3];
    const float* qkv_b  = (const float*)d_in[4];
    const float* proj_w = (const float*)d_in[5];
    const float* proj_b = (const float*)d_in[6];
    const float* btab   = (const float*)d_in[7];
    const float* n2g    = (const float*)d_in[8];
    const float* n2b    = (const float*)d_in[9];
    const float* w1     = (const float*)d_in[10];
    const float* b1     = (const float*)d_in[11];
    const float* w2     = (const float*)d_in[12];
    const float* b2     = (const float*)d_in[13];

    char* ws = (char*)d_ws;
    bf16_t* win      = (bf16_t*)(ws);
    bf16_t* qkvbuf   = (bf16_t*)(ws + (size_t)T_TOK * 256 * 2);
    bf16_t* mlp1_buf = (bf16_t*)(ws);                       // aliases win+qkvbuf after attn/proj
    bf16_t* h2       = (bf16_t*)(ws + (size_t)T_TOK * 2048);
    char* wtp        = ws + (size_t)T_TOK * 2048 + (size_t)T_TOK * 512;
    bf16_t* wt_qkv   = (bf16_t*)wtp;               // [768][256]
    bf16_t* wt_proj  = wt_qkv + 768 * 256;         // [256][256]
    bf16_t* wt_mlp1  = wt_proj + 256 * 256;        // [1024][256]
    bf16_t* wt_mlp2  = wt_mlp1 + 1024 * 256;       // [256][1024]
    float* xmid      = (float*)d_out;

    transpose_cast<<<768, 256, 0, stream>>>(qkv_w, wt_qkv, 256, 768);
    transpose_cast<<<256, 256, 0, stream>>>(proj_w, wt_proj, 256, 256);
    transpose_cast<<<1024, 256, 0, stream>>>(w1, wt_mlp1, 256, 1024);
    transpose_cast<<<1024, 256, 0, stream>>>(w2, wt_mlp2, 1024, 256);

    ln_kernel<1><<<T_TOK / 4, 256, 0, stream>>>(x, n1g, n1b, win);
    // QKV GEMM  [T,256] x [256,768]
    gemm128<0><<<(T_TOK / 128) * (768 / 128), 256, 0, stream>>>(win, wt_qkv, qkv_b, 768, 256,
                                                                qkvbuf, nullptr, nullptr);
    attn_mfma<<<2048 * 2, 256, 0, stream>>>(qkvbuf, btab, win);
    // proj GEMM + window reverse + unshift + residual -> xmid (= d_out)
    gemm128<3><<<(T_TOK / 128) * (256 / 128), 256, 0, stream>>>(win, wt_proj, proj_b, 256, 256,
                                                                nullptr, xmid, x);
    // LN2
    ln_kernel<0><<<T_TOK / 4, 256, 0, stream>>>(xmid, n2g, n2b, h2);
    // MLP1 + GELU  [T,256] x [256,1024]
    gemm128<1><<<(T_TOK / 128) * (1024 / 128), 256, 0, stream>>>(h2, wt_mlp1, b1, 1024, 256,
                                                                 mlp1_buf, nullptr, nullptr);
    // MLP2 + residual  [T,1024] x [1024,256] -> d_out
    gemm128<2><<<(T_TOK / 128) * (256 / 128), 256, 0, stream>>>(mlp1_buf, wt_mlp2, b2, 256, 1024,
                                                                nullptr, xmid, xmid);
}

// Round 6
// 546.992 us; speedup vs baseline: 1.3829x; 1.0702x over previous
//
#include <hip/hip_runtime.h>
#include <hip/hip_bf16.h>
#include <math.h>

typedef __bf16 bf16_t;
typedef __attribute__((ext_vector_type(8))) __bf16 bf16x8;
typedef __attribute__((ext_vector_type(4))) __bf16 bf16x4;
typedef __attribute__((ext_vector_type(4))) float f32x4;

#define T_TOK 100352      // 32 * 3136 tokens (= Bw*N = 2048*49)
#define DIMC 256
#define HEADS 8
#define HD 32
#define NTOK 49
#define SHIFT3 3
#define HH 56
#define SCALE_QK 0.17677669529663687f

__device__ __forceinline__ int xrow_of(int rr) {
    int wi = rr / 49; int t = rr - wi * 49;
    int b = wi >> 6; int w64 = wi & 63;
    int wh = w64 >> 3, ww = w64 & 7;
    int i = t / 7, j = t - i * 7;
    int hy = wh * 7 + i, wy = ww * 7 + j;
    int hx = hy + SHIFT3; if (hx >= HH) hx -= HH;
    int wx = wy + SHIFT3; if (wx >= HH) wx -= HH;
    return b * (HH * HH) + hx * HH + wx;
}

// ---------------- weight transpose + bf16 cast:  W[K][Nc] -> WT[Nc][K] ----------------
__global__ __launch_bounds__(256) void transpose_cast(const float* __restrict__ W,
                                                      bf16_t* __restrict__ WT,
                                                      int K, int Nc) {
    int t = blockIdx.x * 256 + threadIdx.x;
    int k = t / Nc, c = t - k * Nc;
    WT[(size_t)c * K + k] = (bf16_t)W[t];
}

// ---------------- LayerNorm (+optional window gather) + bf16 cast ----------------
template <int MAP>
__global__ __launch_bounds__(256) void ln_kernel(const float* __restrict__ x,
                                                 const float* __restrict__ g,
                                                 const float* __restrict__ bsh,
                                                 bf16_t* __restrict__ out) {
    int wv = threadIdx.x >> 6, l = threadIdx.x & 63;
    int r = blockIdx.x * 4 + wv;
    int xr = MAP ? xrow_of(r) : r;
    float4 v = ((const float4*)(x + (size_t)xr * DIMC))[l];
    float s = v.x + v.y + v.z + v.w;
    float sq = v.x * v.x + v.y * v.y + v.z * v.z + v.w * v.w;
    #pragma unroll
    for (int off = 32; off; off >>= 1) {
        s += __shfl_down(s, off);
        sq += __shfl_down(sq, off);
    }
    s = __shfl(s, 0); sq = __shfl(sq, 0);
    float mean = s * (1.f / 256.f);
    float var = sq * (1.f / 256.f) - mean * mean;
    float rstd = rsqrtf(var + 1e-5f);
    float4 gv = ((const float4*)g)[l];
    float4 bv = ((const float4*)bsh)[l];
    bf16x4 o;
    o[0] = (bf16_t)((v.x - mean) * rstd * gv.x + bv.x);
    o[1] = (bf16_t)((v.y - mean) * rstd * gv.y + bv.y);
    o[2] = (bf16_t)((v.z - mean) * rstd * gv.z + bv.z);
    o[3] = (bf16_t)((v.w - mean) * rstd * gv.w + bv.w);
    *(bf16x4*)(out + (size_t)r * DIMC + l * 4) = o;
}

// ---------------- pipelined bf16 MFMA GEMM: 128x128 tile, BK=64, 2-deep counted vmcnt ----
// LDS layout per buffer: [128 rows][64 k] bf16, 16B chunk c of row r stored at chunk (c^(r&7))
// (pre-swizzled global source; reads XOR the same way -> 2-way bank spread, free).
// EPI: 0 = bias, bf16 | 1 = bias+gelu, bf16 | 2 = bias+resid, f32 | 3 = bias+scatter+resid, f32
template <int EPI, int KT>
__global__ __launch_bounds__(256) void gemm128(const bf16_t* __restrict__ A,
                                               const bf16_t* __restrict__ BT,
                                               const float* __restrict__ bias,
                                               int Nc,
                                               bf16_t* __restrict__ outb,
                                               float* __restrict__ outf,
                                               const float* __restrict__ resid) {
    constexpr int NS = KT / 64;
    __shared__ bf16_t As[2][128 * 64];
    __shared__ bf16_t Bs[2][128 * 64];
    int tid = threadIdx.x;
    int wv = tid >> 6, l = tid & 63;
    int wr = wv >> 1, wc = wv & 1;
    int nTilesN = Nc >> 7;
    // XCD-chunked swizzle (grid always % 8 == 0)
    int qn = gridDim.x >> 3;
    int lb = (blockIdx.x & 7) * qn + (blockIdx.x >> 3);
    int bm = lb / nTilesN, bn = lb - bm * nTilesN;
    size_t row0 = (size_t)bm * 128;
    int col0 = bn * 128;

    const char* Abase = (const char*)(A + row0 * KT);
    const char* Bbase = (const char*)(BT + (size_t)col0 * KT);
    const size_t ldb = (size_t)KT * 2;

    // staging: 1024 16B-chunks per matrix per K-step; 4 insts/thread each (8 total)
    auto STAGE = [&](int buf, int kk) {
        #pragma unroll
        for (int it = 0; it < 4; ++it) {
            int ci = tid + it * 256;
            int row = ci >> 3, ch = ci & 7;
            int sc = ch ^ (row & 7);
            __builtin_amdgcn_global_load_lds(
                (const __attribute__((address_space(1))) void*)(Abase + (size_t)row * ldb + (size_t)kk * 2 + sc * 16),
                (__attribute__((address_space(3))) void*)((char*)As[buf] + ci * 16), 16, 0, 0);
            __builtin_amdgcn_global_load_lds(
                (const __attribute__((address_space(1))) void*)(Bbase + (size_t)row * ldb + (size_t)kk * 2 + sc * 16),
                (__attribute__((address_space(3))) void*)((char*)Bs[buf] + ci * 16), 16, 0, 0);
        }
    };

    f32x4 acc[4][4] = {};
    const int lr = l & 15, g4 = l >> 4;

    STAGE(0, 0);
    if (NS > 1) STAGE(1, 64);

    #pragma unroll
    for (int s = 0; s < NS; ++s) {
        if (s + 1 < NS) { asm volatile("s_waitcnt vmcnt(8)" ::: "memory"); }
        else            { asm volatile("s_waitcnt vmcnt(0)" ::: "memory"); }
        __builtin_amdgcn_s_barrier();
        __builtin_amdgcn_sched_barrier(0);
        int buf = s & 1;
        #pragma unroll
        for (int ks = 0; ks < 2; ++ks) {
            bf16x8 a[4], b[4];
            #pragma unroll
            for (int mt = 0; mt < 4; ++mt) {
                int rr = wr * 64 + mt * 16 + lr;
                int c = (ks * 4 + g4) ^ (rr & 7);
                a[mt] = *(const bf16x8*)((char*)As[buf] + rr * 128 + c * 16);
            }
            #pragma unroll
            for (int nt = 0; nt < 4; ++nt) {
                int rc = wc * 64 + nt * 16 + lr;
                int c = (ks * 4 + g4) ^ (rc & 7);
                b[nt] = *(const bf16x8*)((char*)Bs[buf] + rc * 128 + c * 16);
            }
            __builtin_amdgcn_s_setprio(1);
            #pragma unroll
            for (int mt = 0; mt < 4; ++mt)
                #pragma unroll
                for (int nt = 0; nt < 4; ++nt)
                    acc[mt][nt] = __builtin_amdgcn_mfma_f32_16x16x32_bf16(a[mt], b[nt], acc[mt][nt], 0, 0, 0);
            __builtin_amdgcn_s_setprio(0);
        }
        __builtin_amdgcn_s_barrier();
        __builtin_amdgcn_sched_barrier(0);
        if (s + 2 < NS) STAGE(buf, (s + 2) * 64);
    }

    #pragma unroll
    for (int m = 0; m < 4; ++m) {
        #pragma unroll
        for (int i = 0; i < 4; ++i) {
            int rr = (int)row0 + wr * 64 + m * 16 + g4 * 4 + i;
            size_t orow = (EPI == 3) ? (size_t)xrow_of(rr) * DIMC : (size_t)rr * Nc;
            #pragma unroll
            for (int n = 0; n < 4; ++n) {
                int cc = col0 + wc * 64 + n * 16 + lr;
                float v = acc[m][n][i] + bias[cc];
                if (EPI == 0) {
                    outb[(size_t)rr * Nc + cc] = (bf16_t)v;
                } else if (EPI == 1) {
                    float t3 = v + 0.044715f * v * v * v;
                    float e = __expf(-1.5957691216057308f * t3);
                    float gl = v * __builtin_amdgcn_rcpf(1.f + e);
                    outb[(size_t)rr * Nc + cc] = (bf16_t)gl;
                } else if (EPI == 2) {
                    size_t o = (size_t)rr * Nc + cc;
                    outf[o] = v + resid[o];
                } else {
                    size_t o = orow + cc;
                    outf[o] = v + resid[o];
                }
            }
        }
    }
}

// ---------------- MFMA windowed attention ----------------
__global__ __launch_bounds__(256) void attn_mfma(const bf16_t* __restrict__ qkv,
                                                 const float* __restrict__ bt,
                                                 bf16_t* __restrict__ out) {
    __shared__ __align__(16) char lds[4][12800];
    int wv = threadIdx.x >> 6, l = threadIdx.x & 63;
    int head = ((blockIdx.x & 1) << 2) | wv;
    int wi = blockIdx.x >> 1;
    char* W = lds[wv];
    bf16_t* Vt = (bf16_t*)(W + 8192);          // [32][72]
    size_t rowbase = (size_t)wi * NTOK;
    const bf16_t* src = qkv + rowbase * 768 + head * HD;

    int w64 = wi & 63;
    int wh = w64 >> 3, ww = w64 & 7;
    bool lastH = (wh == 7), lastW = (ww == 7);
    bool masked = lastH || lastW;

    #pragma unroll
    for (int it = 0; it < 4; ++it) {
        int t = l + it * 64;
        int r = t >> 2, g = t & 3;
        if (r < NTOK) {
            bf16x8 qv = *(const bf16x8*)(src + (size_t)r * 768 + g * 8);
            bf16x8 kv = *(const bf16x8*)(src + (size_t)r * 768 + 256 + g * 8);
            int sa = (r * 64 + g * 16) ^ ((r & 7) << 4);
            *(bf16x8*)(W + sa) = qv;
            *(bf16x8*)(W + 4096 + sa) = kv;
        }
    }
    #pragma unroll
    for (int it = 0; it < 4; ++it) {
        int t = l + it * 64;
        int m = t >> 2, dc = t & 3;
        if (m < NTOK) {
            bf16x8 vv = *(const bf16x8*)(src + (size_t)m * 768 + 512 + dc * 8);
            #pragma unroll
            for (int j = 0; j < 8; ++j) Vt[(dc * 8 + j) * 72 + m] = vv[j];
        } else {
            #pragma unroll
            for (int j = 0; j < 8; ++j) Vt[(dc * 8 + j) * 72 + m] = (bf16_t)0.f;
        }
    }

    int lr = l & 15, g4 = l >> 4;

    bf16x8 a[4], b[4];
    #pragma unroll
    for (int mt = 0; mt < 4; ++mt) {
        int r = mt * 16 + lr;
        int sa = (r * 64 + g4 * 16) ^ ((r & 7) << 4);
        a[mt] = *(const bf16x8*)(W + sa);
        b[mt] = *(const bf16x8*)(W + 4096 + sa);
    }
    f32x4 z = {0.f, 0.f, 0.f, 0.f};
    f32x4 S[4][4];
    #pragma unroll
    for (int mt = 0; mt < 4; ++mt)
        #pragma unroll
        for (int nt = 0; nt < 4; ++nt)
            S[mt][nt] = __builtin_amdgcn_mfma_f32_16x16x32_bf16(a[mt], b[nt], z, 0, 0, 0);

    int i2[4], j2[4], reg2[4];
    #pragma unroll
    for (int nt = 0; nt < 4; ++nt) {
        int cm = nt * 16 + lr;
        i2[nt] = (cm * 147) >> 10;
        j2[nt] = cm - i2[nt] * 7;
        int rh = lastH ? ((i2[nt] < 4) ? 1 : 2) : 0;
        int rw = lastW ? ((j2[nt] < 4) ? 1 : 2) : 0;
        reg2[nt] = rh * 3 + rw;
    }

    #pragma unroll
    for (int mt = 0; mt < 4; ++mt) {
        #pragma unroll
        for (int i = 0; i < 4; ++i) {
            int rn = mt * 16 + g4 * 4 + i;
            bool rowok = rn < NTOK;
            int i1 = (rn * 147) >> 10, j1 = rn - i1 * 7;
            int rh1 = lastH ? ((i1 < 4) ? 1 : 2) : 0;
            int rw1 = lastW ? ((j1 < 4) ? 1 : 2) : 0;
            int reg1 = rh1 * 3 + rw1;
            float sv[4];
            #pragma unroll
            for (int nt = 0; nt < 4; ++nt) {
                int cm = nt * 16 + lr;
                float sc;
                if (rowok && cm < NTOK) {
                    sc = S[mt][nt][i] * SCALE_QK;
                    sc += bt[((i1 - i2[nt] + 6) + 13 * (j1 - j2[nt] + 6)) * 8 + head];
                    if (masked && (reg1 != reg2[nt])) sc -= 100.f;
                } else {
                    sc = -1e30f;
                }
                sv[nt] = sc;
            }
            float mx = fmaxf(fmaxf(sv[0], sv[1]), fmaxf(sv[2], sv[3]));
            mx = fmaxf(mx, __shfl_xor(mx, 1));
            mx = fmaxf(mx, __shfl_xor(mx, 2));
            mx = fmaxf(mx, __shfl_xor(mx, 4));
            mx = fmaxf(mx, __shfl_xor(mx, 8));
            float e[4];
            float sum = 0.f;
            #pragma unroll
            for (int nt = 0; nt < 4; ++nt) { e[nt] = __expf(sv[nt] - mx); sum += e[nt]; }
            sum += __shfl_xor(sum, 1);
            sum += __shfl_xor(sum, 2);
            sum += __shfl_xor(sum, 4);
            sum += __shfl_xor(sum, 8);
            float inv = 1.f / sum;
            #pragma unroll
            for (int nt = 0; nt < 4; ++nt) {
                int cm = nt * 16 + lr;
                int pa = (rn * 128 + cm * 2) ^ ((rn & 7) << 4);
                *(bf16_t*)(W + pa) = (bf16_t)(e[nt] * inv);
            }
        }
    }

    f32x4 o[4][2] = {};
    #pragma unroll
    for (int ks = 0; ks < 2; ++ks) {
        bf16x8 pa[4], vb[2];
        #pragma unroll
        for (int mt = 0; mt < 4; ++mt) {
            int r = mt * 16 + lr;
            int ad = (r * 128 + ks * 64 + g4 * 16) ^ ((r & 7) << 4);
            pa[mt] = *(const bf16x8*)(W + ad);
        }
        #pragma unroll
        for (int dt = 0; dt < 2; ++dt) {
            int d = dt * 16 + lr;
            vb[dt] = *(const bf16x8*)((char*)Vt + d * 144 + ks * 64 + g4 * 16);
        }
        #pragma unroll
        for (int mt = 0; mt < 4; ++mt)
            #pragma unroll
            for (int dt = 0; dt < 2; ++dt)
                o[mt][dt] = __builtin_amdgcn_mfma_f32_16x16x32_bf16(pa[mt], vb[dt], o[mt][dt], 0, 0, 0);
    }

    #pragma unroll
    for (int mt = 0; mt < 4; ++mt) {
        #pragma unroll
        for (int i = 0; i < 4; ++i) {
            int n = mt * 16 + g4 * 4 + i;
            if (n < NTOK) {
                #pragma unroll
                for (int dt = 0; dt < 2; ++dt) {
                    out[(rowbase + n) * DIMC + head * HD + dt * 16 + lr] = (bf16_t)o[mt][dt][i];
                }
            }
        }
    }
}

extern "C" void kernel_launch(void* const* d_in, const int* in_sizes, int n_in,
                              void* d_out, int out_size, void* d_ws, size_t ws_size,
                              hipStream_t stream) {
    const float* x      = (const float*)d_in[0];
    const float* n1g    = (const float*)d_in[1];
    const float* n1b    = (const float*)d_in[2];
    const float* qkv_w  = (const float*)d_in[3];
    const float* qkv_b  = (const float*)d_in[4];
    const float* proj_w = (const float*)d_in[5];
    const float* proj_b = (const float*)d_in[6];
    const float* btab   = (const float*)d_in[7];
    const float* n2g    = (const float*)d_in[8];
    const float* n2b    = (const float*)d_in[9];
    const float* w1     = (const float*)d_in[10];
    const float* b1     = (const float*)d_in[11];
    const float* w2     = (const float*)d_in[12];
    const float* b2     = (const float*)d_in[13];

    char* ws = (char*)d_ws;
    bf16_t* win      = (bf16_t*)(ws);
    bf16_t* qkvbuf   = (bf16_t*)(ws + (size_t)T_TOK * 256 * 2);
    bf16_t* mlp1_buf = (bf16_t*)(ws);                       // aliases win+qkvbuf after attn/proj
    bf16_t* h2       = (bf16_t*)(ws + (size_t)T_TOK * 2048);
    char* wtp        = ws + (size_t)T_TOK * 2048 + (size_t)T_TOK * 512;
    bf16_t* wt_qkv   = (bf16_t*)wtp;               // [768][256]
    bf16_t* wt_proj  = wt_qkv + 768 * 256;         // [256][256]
    bf16_t* wt_mlp1  = wt_proj + 256 * 256;        // [1024][256]
    bf16_t* wt_mlp2  = wt_mlp1 + 1024 * 256;       // [256][1024]
    float* xmid      = (float*)d_out;

    transpose_cast<<<768, 256, 0, stream>>>(qkv_w, wt_qkv, 256, 768);
    transpose_cast<<<256, 256, 0, stream>>>(proj_w, wt_proj, 256, 256);
    transpose_cast<<<1024, 256, 0, stream>>>(w1, wt_mlp1, 256, 1024);
    transpose_cast<<<1024, 256, 0, stream>>>(w2, wt_mlp2, 1024, 256);

    ln_kernel<1><<<T_TOK / 4, 256, 0, stream>>>(x, n1g, n1b, win);
    // QKV GEMM  [T,256] x [256,768]
    gemm128<0, 256><<<(T_TOK / 128) * (768 / 128), 256, 0, stream>>>(win, wt_qkv, qkv_b, 768,
                                                                     qkvbuf, nullptr, nullptr);
    attn_mfma<<<2048 * 2, 256, 0, stream>>>(qkvbuf, btab, win);
    // proj GEMM + window reverse + unshift + residual -> xmid (= d_out)
    gemm128<3, 256><<<(T_TOK / 128) * (256 / 128), 256, 0, stream>>>(win, wt_proj, proj_b, 256,
                                                                     nullptr, xmid, x);
    // LN2
    ln_kernel<0><<<T_TOK / 4, 256, 0, stream>>>(xmid, n2g, n2b, h2);
    // MLP1 + GELU  [T,256] x [256,1024]
    gemm128<1, 256><<<(T_TOK / 128) * (1024 / 128), 256, 0, stream>>>(h2, wt_mlp1, b1, 1024,
                                                                      mlp1_buf, nullptr, nullptr);
    // MLP2 + residual  [T,1024] x [1024,256] -> d_out
    gemm128<2, 1024><<<(T_TOK / 128) * (256 / 128), 256, 0, stream>>>(mlp1_buf, wt_mlp2, b2, 256,
                                                                      nullptr, xmid, xmid);
}